// Round 9
// baseline (2018.383 us; speedup 1.0000x reference)
//
#include <hip/hip_runtime.h>
#include <stdint.h>

// ---------------- problem constants ----------------
#define NSTEP 100
#define FEAT  1024
#define SPIN_CAP (1 << 20)

typedef __attribute__((ext_vector_type(8)))  short short8;
typedef __attribute__((ext_vector_type(4)))  float fx4;

// ---------------- workspace layout (bytes) ----------------
// Exchange: parity-double-buffered, 8 groups x (32 rows x 1024 cols) bf16.
// DATA: XCD-L2-local sc0 when group is XCD-uniform (R5/R7-proven), else sc1.
// CONTROL: agent-scope atomics at the LLC (R3/R5/R7-proven).
// R9: barrier-free main loop. Each wave owns a 16x16 tile (rh=row-half,
// ch=col-half), full-K GEMM via mfma 16x16x32 -> no K-reduction, no
// __syncthreads after the prelude. Flags per (group, rh, nj), +1 per ch-wave,
// consumer target 2*(t+1).
// Overwrite safety (parity dbuf): a writer of step t+2 (same parity as t)
// must have seen ec3flag/ca1flag[rh][nj'] == 2(t+3)/2(t+2) for ALL nj', which
// transitively requires every same-rh wave to have finished reading step t;
// different-rh waves touch disjoint rows. So no clobber.
// Element (group-local row m, col c) at short index ((c>>3)*32+m)*8+(c&7).
#define OFF_EC3   0u
#define OFF_CA1   (1u << 20)
#define OFF_DRIVE (2u << 20)
#define OFF_EC3F  (OFF_DRIVE + (512u << 10))   // 512 ints: [bi][rh][nj]
#define OFF_CA1F  (OFF_EC3F + 4096u)
#define OFF_DRVF  (OFF_CA1F + 4096u)
#define OFF_GRP   (OFF_DRVF + 4096u)           // grpmask[8] @+0, grpcnt[8] @+512
#define WS_NEED   (OFF_GRP + 4096u)

#define GSTRIDE 32768                  // shorts per group
#define PSTRIDE (8 * GSTRIDE)          // shorts per parity buffer

// ---------------- output layout (float elems) ----------------
#define O_ACT 0
#define O_E3H 512
#define O_E5H (512 + 102400)
#define O_CAH (512 + 204800)
#define O_E3  (512 + 307200)
#define O_E5  (O_E3 + 262144)
#define O_CA  (O_E5 + 262144)

// ---------------- LDS layout (bytes) ----------------
#define LDS_W1    0
#define LDS_W2    65536
#define LDS_DRV   131072               // 100*32 f32 = 12800
#define LDS_UNI   143872
#define LDS_TOTAL 143888               // <= 163840

__device__ __forceinline__ unsigned short f2bf(float x) {
  uint32_t u = __builtin_bit_cast(uint32_t, x);
  uint32_t r = (u + 0x7FFFu + ((u >> 16) & 1u)) >> 16;   // RNE
  return (unsigned short)r;
}
__device__ __forceinline__ float sigm(float x) { return 1.0f / (1.0f + __expf(-x)); }

#define VM_DRAIN() asm volatile("s_waitcnt vmcnt(0)" ::: "memory")

__device__ __forceinline__ void llc_store_f32(float* p, float v) {
  asm volatile("global_store_dword %0, %1, off sc0 sc1" :: "v"(p), "v"(v) : "memory");
}
// bf16 exchange store (2B): uni -> XCD L2; else LLC coherent
__device__ __forceinline__ void ex_store16(void* p, unsigned short v, bool uni) {
  unsigned int vi = v;
  if (uni) asm volatile("global_store_short %0, %1, off sc0"     :: "v"(p), "v"(vi) : "memory");
  else     asm volatile("global_store_short %0, %1, off sc0 sc1" :: "v"(p), "v"(vi) : "memory");
}
// control plane: agent scope at the LLC, always
__device__ __forceinline__ void flag_add(int* p) {
  __hip_atomic_fetch_add(p, 1, __ATOMIC_RELAXED, __HIP_MEMORY_SCOPE_AGENT);
}
__device__ __forceinline__ int flag_peek(const int* p) {
  return __hip_atomic_load(p, __ATOMIC_RELAXED, __HIP_MEMORY_SCOPE_AGENT);
}
__device__ __forceinline__ void flag_wait(const int* p, int tgt) {
  int sp = 0;
  while (flag_peek(p) < tgt) {
    __builtin_amdgcn_s_sleep(1);
    if (++sp > SPIN_CAP) break;        // bounded
  }
}

// ---- A-load helpers: 16 loads at 1024-short (2KB) stride ----
#define ISS16U(buf, p, base)                                                  \
  _Pragma("unroll") for (int j = 0; j < 16; ++j)                              \
    asm volatile("global_load_dwordx4 %0, %1, off sc0"                        \
                 : "=v"((buf)[j]) : "v"((p) + ((base) + j) * 1024) : "memory");
#define ISS16L(buf, p, base)                                                  \
  _Pragma("unroll") for (int j = 0; j < 16; ++j)                              \
    asm volatile("global_load_dwordx4 %0, %1, off sc0 sc1"                    \
                 : "=v"((buf)[j]) : "v"((p) + ((base) + j) * 1024) : "memory");
#define WAITVM(n, b)                                                          \
  asm volatile("s_waitcnt vmcnt(" #n ")"                                      \
    : "+v"((b)[0]), "+v"((b)[1]), "+v"((b)[2]), "+v"((b)[3]),                 \
      "+v"((b)[4]), "+v"((b)[5]), "+v"((b)[6]), "+v"((b)[7]),                 \
      "+v"((b)[8]), "+v"((b)[9]), "+v"((b)[10]), "+v"((b)[11]),               \
      "+v"((b)[12]), "+v"((b)[13]), "+v"((b)[14]), "+v"((b)[15]) :: "memory")

// One wave's 16x16 full-K GEMM: 32 mfma_16x16x32, A from global (pipelined
// 2x16), B from LDS (chunked: [n=16ch+m15][k] at kt*1024 + q*256 + n*8).
// A operand: A[m=lane&15][k=8q+j] (guide-verified); C: col=lane&15,
// row=4q+reg (m89-verified).
template <bool UNI>
__device__ __forceinline__ fx4 gemm16(const short* __restrict__ ap,
                                      const short* __restrict__ bp) {
  short8 A0[16], A1[16];
  fx4 a0 = 0.0f, a1 = 0.0f, a2 = 0.0f, a3 = 0.0f;
  if (UNI) { ISS16U(A0, ap, 0); ISS16U(A1, ap, 16); }
  else     { ISS16L(A0, ap, 0); ISS16L(A1, ap, 16); }
  WAITVM(16, A0);
#pragma unroll
  for (int j = 0; j < 16; ++j) {
    short8 b = *(const short8*)(bp + j * 1024);
    switch (j & 3) {
      case 0: a0 = __builtin_amdgcn_mfma_f32_16x16x32_bf16(A0[j], b, a0, 0, 0, 0); break;
      case 1: a1 = __builtin_amdgcn_mfma_f32_16x16x32_bf16(A0[j], b, a1, 0, 0, 0); break;
      case 2: a2 = __builtin_amdgcn_mfma_f32_16x16x32_bf16(A0[j], b, a2, 0, 0, 0); break;
      default:a3 = __builtin_amdgcn_mfma_f32_16x16x32_bf16(A0[j], b, a3, 0, 0, 0); break;
    }
  }
  WAITVM(0, A1);
#pragma unroll
  for (int j = 0; j < 16; ++j) {
    short8 b = *(const short8*)(bp + (16 + j) * 1024);
    switch (j & 3) {
      case 0: a0 = __builtin_amdgcn_mfma_f32_16x16x32_bf16(A1[j], b, a0, 0, 0, 0); break;
      case 1: a1 = __builtin_amdgcn_mfma_f32_16x16x32_bf16(A1[j], b, a1, 0, 0, 0); break;
      case 2: a2 = __builtin_amdgcn_mfma_f32_16x16x32_bf16(A1[j], b, a2, 0, 0, 0); break;
      default:a3 = __builtin_amdgcn_mfma_f32_16x16x32_bf16(A1[j], b, a3, 0, 0, 0); break;
    }
  }
  return (a0 + a1) + (a2 + a3);
}

extern "C" __global__ void __launch_bounds__(256, 1)
hpcrnn_kernel(const int* __restrict__ cue,
              const float* __restrict__ ec3_last,
              const float* __restrict__ ec5_last,
              const float* __restrict__ ca1bias,
              const float* __restrict__ wca3ca1,
              const float* __restrict__ wec3ca1,
              const float* __restrict__ wca1ec5,
              const float* __restrict__ wca1act,
              const float* __restrict__ actbias,
              float* __restrict__ out,
              char* __restrict__ ws)
{
  extern __shared__ __attribute__((aligned(16))) char lds[];
  short* w1l  = (short*)(lds + LDS_W1);
  short* w2l  = (short*)(lds + LDS_W2);
  float* drvl = (float*)(lds + LDS_DRV);
  int*   unil = (int*)(lds + LDS_UNI);

  const int tid = threadIdx.x;
  const int bi  = blockIdx.x & 7;    // batch group; %8 == XCD residue heuristic
  const int nj  = blockIdx.x >> 3;   // N chunk (32 cols)
  const int R   = bi * 32, C = nj * 32;
  const int lane = tid & 63, wv = tid >> 6;
  const int rh = wv >> 1, ch = wv & 1;     // wave's (row-half, col-half) tile
  const int q = lane >> 4, m15 = lane & 15;

  short* ec3buf = (short*)(ws + OFF_EC3);
  short* ca1buf = (short*)(ws + OFF_CA1);
  float* driveg = (float*)(ws + OFF_DRIVE);
  int*   ec3flag = (int*)(ws + OFF_EC3F);
  int*   ca1flag = (int*)(ws + OFF_CA1F);
  int*   drvflag = (int*)(ws + OFF_DRVF);
  int*   grpmask = (int*)(ws + OFF_GRP);
  int*   grpcnt  = (int*)(ws + OFF_GRP + 512);
  const int fbi = bi * 64;                 // flag block: [bi][rh][nj]
  const size_t gbase = (size_t)bi * GSTRIDE;

  // ---- post group membership (XCD id), agent scope ----
  if (tid == 0) {
    int xcc;
    asm volatile("s_getreg_b32 %0, hwreg(HW_REG_XCC_ID)" : "=s"(xcc));
    __hip_atomic_fetch_or(&grpmask[bi], 1 << (xcc & 31), __ATOMIC_RELAXED, __HIP_MEMORY_SCOPE_AGENT);
    __hip_atomic_fetch_add(&grpcnt[bi], 1, __ATOMIC_RELAXED, __HIP_MEMORY_SCOPE_AGENT);
  }

  // ---- weights -> LDS, bf16, CHUNKED [g=(k>>3)][n=0..31][k&7] ----
  {
    const int c = tid & 31;
    for (int k = tid >> 5; k < FEAT; k += 8) {
      const int idx = ((k >> 3) * 32 + c) * 8 + (k & 7);
      w1l[idx] = (short)f2bf(wec3ca1[k * FEAT + C + c]);
      w2l[idx] = (short)f2bf(wca1ec5[k * FEAT + C + c]);
    }
  }

  // ---- per-wave state init (16x16 C-layout: col=m15, row=4q+r) + initial
  //      ec3 publish via sc1 (readable by either consumer mode; R8-proven) ----
  float ec3s[4], ec5s[4], ca1s[4];
  const int cg = C + 16 * ch + m15;                  // this lane's output col
  const size_t spbase = ((size_t)(cg >> 3) * 32 + 16 * rh + 4 * q) * 8 + (cg & 7);
#pragma unroll
  for (int r = 0; r < 4; ++r) {
    const int row = 16 * rh + 4 * q + r;             // group-local row
    ec3s[r] = ec3_last[(size_t)(R + row) * FEAT + cg];
    ec5s[r] = ec5_last[(size_t)(R + row) * FEAT + cg];
    ca1s[r] = 0.0f;
    ex_store16(ec3buf + gbase + spbase + r * 8, f2bf(ec3s[r]), false);
  }
  VM_DRAIN();
  if (lane == 0) flag_add(&ec3flag[fbi + rh * 32 + nj]);

  // ---- drive: block covers cols C..C+31 for t === bi (mod 8); t-list split
  //      across the 4 waves (R8-proven); per-wave drvflag add; tgt 32 ----
  {
    int cnt = 0;
    const int col = lane & 31, kh = lane >> 5;
    for (int t = bi; t < NSTEP; t += 8, ++cnt) {
      if ((cnt & 3) != wv) continue;
      float part = 0.0f;
      const float tf = (float)t;
      for (int c = kh * 512; c < kh * 512 + 512; ++c) {
        float d = (float)c * (100.0f / 1023.0f) - tf;
        part += __expf(d * d * -0.02f) * wca3ca1[c * FEAT + C + col];
      }
      part += __shfl_xor(part, 32);
      if (lane < 32) llc_store_f32(driveg + t * FEAT + C + col, part);
    }
    VM_DRAIN();
    if (lane == 0) flag_add(&drvflag[nj]);
  }

  // ---- resolve group XCD-uniformity; wait drive; stage drive to LDS ----
  if (tid == 0) {
    flag_wait(&grpcnt[bi], 32);
    int cnt = flag_peek(&grpcnt[bi]);
    int mv  = __hip_atomic_load(&grpmask[bi], __ATOMIC_RELAXED, __HIP_MEMORY_SCOPE_AGENT);
    unil[0] = (cnt >= 32 && __popc(mv) == 1) ? 1 : 0;
    flag_wait(&drvflag[nj], 32);
  }
  __syncthreads();
  for (int i = tid; i < NSTEP * 32; i += 256) {
    float v;
    asm volatile("global_load_dword %0, %1, off sc0 sc1"
                 : "=v"(v) : "v"(driveg + (i >> 5) * FEAT + C + (i & 31)) : "memory");
    asm volatile("s_waitcnt vmcnt(0)" : "+v"(v) :: "memory");
    drvl[i] = v;
  }
  __syncthreads();                       // last barrier; main loop is barrier-free
  const bool uni = (unil[0] != 0);

  const float biasv = ca1bias[cg];
  const float wa0 = wca1act[cg * 2 + 0];
  const float wa1 = wca1act[cg * 2 + 1];
  const size_t abase = (size_t)q * 256 + (16 * rh + m15) * 8;   // A-frag base
  const short* bp1 = w1l + q * 256 + (16 * ch + m15) * 8;       // B-frag base
  const short* bp2 = w2l + q * 256 + (16 * ch + m15) * 8;

  // =================== main recurrence (per-wave, no barriers) ===================
  for (int t = 0; t < NSTEP; ++t) {
    const size_t par = (size_t)(t & 1) * PSTRIDE;
    const int tgt = 2 * (t + 1);

    // ---- phase 1: ca1 = relu(drive*(1+sig(ec3@w1)) - bias) ----
    if (lane < 32) flag_wait(&ec3flag[fbi + rh * 32 + lane], tgt);
    {
      fx4 dot;
      const short* ap = ec3buf + par + gbase + abase;
      if (uni) dot = gemm16<true >(ap, bp1);
      else     dot = gemm16<false>(ap, bp1);
      const float drv_t = drvl[t * 32 + 16 * ch + m15];
      short* cb = ca1buf + par + gbase + spbase;
#pragma unroll
      for (int r = 0; r < 4; ++r) {
        float v = drv_t * (1.0f + sigm(dot[r])) - biasv;
        ca1s[r] = fmaxf(v, 0.0f);
        ex_store16(cb + r * 8, f2bf(ca1s[r]), uni);
      }
      VM_DRAIN();
      if (lane == 0) flag_add(&ca1flag[fbi + rh * 32 + nj]);
      if (bi == 0 && rh == 0 && lane < 16)            // row 0 = (q=0, r=0)
        out[O_CAH + t * FEAT + cg] = ca1s[0];
    }

    // ---- phase 2: ec5 += ca1@w2 ; squash ; ec3 = ec5*ec3 ; cue ----
    if (lane < 32) flag_wait(&ca1flag[fbi + rh * 32 + lane], tgt);
    {
      fx4 dot;
      const short* ap = ca1buf + par + gbase + abase;
      if (uni) dot = gemm16<true >(ap, bp2);
      else     dot = gemm16<false>(ap, bp2);
#pragma unroll
      for (int r = 0; r < 4; ++r) {
        float e5 = ec5s[r] + dot[r];                   // 10*TS = 1.0
        e5 = 0.69f + 0.3f * sigm(4.0f * (e5 - 0.3f));
        ec5s[r] = e5;
        ec3s[r] = e5 * ec3s[r];
      }
      if (t == 16 || t == 24) {
        const int s = (t == 24) ? 1 : 0;
#pragma unroll
        for (int r = 0; r < 4; ++r) {
          const int row = 16 * rh + 4 * q + r;
          int mv = cue[(size_t)(R + row) * 2048 + s * 1024 + cg];
          if (mv) ec3s[r] = 0.4f * ec3s[r] + 0.6f;
        }
      }
      if (t < NSTEP - 1) {
        short* eb = ec3buf + (size_t)((t + 1) & 1) * PSTRIDE + gbase + spbase;
#pragma unroll
        for (int r = 0; r < 4; ++r)
          ex_store16(eb + r * 8, f2bf(ec3s[r]), uni);
        VM_DRAIN();
        if (lane == 0) flag_add(&ec3flag[fbi + rh * 32 + nj]);
      }
      if (bi == 0 && rh == 0 && lane < 16) {
        out[O_E3H + t * FEAT + cg] = ec3s[0];
        out[O_E5H + t * FEAT + cg] = ec5s[0];
      }
    }
  }

  // ---- epilogue: finals + actCell (butterfly over m15, atomic per row) ----
#pragma unroll
  for (int r = 0; r < 4; ++r) {
    const int row = 16 * rh + 4 * q + r;
    out[O_E3 + (size_t)(R + row) * FEAT + cg] = ec3s[r];
    out[O_E5 + (size_t)(R + row) * FEAT + cg] = ec5s[r];
    out[O_CA + (size_t)(R + row) * FEAT + cg] = ca1s[r];
    float p0 = ca1s[r] * wa0;
    float p1 = ca1s[r] * wa1;
#pragma unroll
    for (int off = 1; off < 16; off <<= 1) {
      p0 += __shfl_xor(p0, off);
      p1 += __shfl_xor(p1, off);
    }
    if (m15 == 0) {
      float v = p0; if (nj == 0 && ch == 0) v += actbias[0];
      atomicAdd(&out[O_ACT + (R + row) * 2 + 0], v);
    }
    if (m15 == 1) {
      float v = p1; if (nj == 0 && ch == 0) v += actbias[1];
      atomicAdd(&out[O_ACT + (R + row) * 2 + 1], v);
    }
  }
}

extern "C" void kernel_launch(void* const* d_in, const int* in_sizes, int n_in,
                              void* d_out, int out_size, void* d_ws, size_t ws_size,
                              hipStream_t stream) {
  (void)in_sizes; (void)n_in; (void)out_size;
  if (ws_size < WS_NEED) return;

  const int*   cue      = (const int*)  d_in[0];
  const float* ec3_last = (const float*)d_in[1];
  const float* ec5_last = (const float*)d_in[2];
  // d_in[3] = ca1_last: dead in the reference (overwritten before use)
  const float* ca1bias  = (const float*)d_in[4];
  const float* wca3ca1  = (const float*)d_in[5];
  const float* wec3ca1  = (const float*)d_in[6];
  const float* wca1ec5  = (const float*)d_in[7];
  const float* wca1act  = (const float*)d_in[8];
  const float* actbias  = (const float*)d_in[9];

  char* ws = (char*)d_ws;
  hipMemsetAsync(ws + OFF_EC3F, 0, 4 * 4096, stream);   // flags + rendezvous start at 0
  hipMemsetAsync(d_out, 0, 512 * sizeof(float), stream);

  hipFuncSetAttribute(reinterpret_cast<const void*>(hpcrnn_kernel),
                      hipFuncAttributeMaxDynamicSharedMemorySize, LDS_TOTAL);

  hipLaunchKernelGGL(hpcrnn_kernel, dim3(256), dim3(256), LDS_TOTAL, stream,
                     cue, ec3_last, ec5_last, ca1bias, wca3ca1, wec3ca1,
                     wca1ec5, wca1act, actbias, (float*)d_out, ws);
}

// Round 10
// 750.648 us; speedup vs baseline: 2.6889x; 2.6889x over previous
//
#include <hip/hip_runtime.h>
#include <stdint.h>

// ---------------- problem constants ----------------
#define NSTEP 100
#define FEAT  1024
#define SPIN_CAP (1 << 16)   // ~30ms/wait worst: truly bounded

typedef __attribute__((ext_vector_type(8)))  short short8;
typedef __attribute__((ext_vector_type(4)))  float fx4;
typedef __attribute__((ext_vector_type(16))) float fx16;
typedef __attribute__((ext_vector_type(2)))  unsigned int u32x2;
typedef __attribute__((ext_vector_type(4)))  int i32x4;

// ---------------- workspace layout (bytes) ----------------
// R10 = R7 (best: 740us) with ONLY the poll loop changed (backoff, see
// flag_wait). R8 (single-wave, 1097us) and R9 (per-wave tiles, 2018us) both
// regressed: 4-SIMD MFMA issue parallelism and barrier-aligned straggle
// control are load-bearing. Exchange: parity-double-buffered, 8 groups x
// (32 rows x 1024 cols) bf16. DATA: XCD-L2-local sc0 when group XCD-uniform
// (HW_REG_XCC_ID rendezvous; R5-proven), else LLC sc1. CONTROL: agent-scope
// atomics at the LLC (R3/R5/R7-proven; both XCD-local-flag attempts hung).
// Flags count producer WAVES (wave drains its rows then adds); tgt 4*(t+1).
// Element (group-local row m, col c) at short index ((c>>3)*32+m)*8+(c&7).
#define OFF_EC3   0u
#define OFF_CA1   (1u << 20)
#define OFF_DRIVE (2u << 20)
#define OFF_EC3F  (OFF_DRIVE + (512u << 10))
#define OFF_CA1F  (OFF_EC3F + 4096u)
#define OFF_DRVF  (OFF_CA1F + 4096u)
#define OFF_GRP   (OFF_DRVF + 4096u)   // grpmask[8] @+0, grpcnt[8] @+512
#define WS_NEED   (OFF_GRP + 4096u)

#define GSTRIDE 32768                  // shorts per group (32*1024)
#define PSTRIDE (8 * GSTRIDE)          // shorts per parity buffer

// ---------------- output layout (float elems) ----------------
#define O_ACT 0
#define O_E3H 512
#define O_E5H (512 + 102400)
#define O_CAH (512 + 204800)
#define O_E3  (512 + 307200)
#define O_E5  (O_E3 + 262144)
#define O_CA  (O_E5 + 262144)

// ---------------- LDS layout (bytes) ----------------
#define LDS_W1    0
#define LDS_W2    65536
#define LDS_RED4  131072               // 4*1024 f32 = 16384
#define LDS_DRV   147456               // 100*32 f32 = 12800
#define LDS_UNI   160256               // 1 int
#define LDS_TOTAL 160272               // <= 163840

__device__ __forceinline__ unsigned short f2bf(float x) {
  uint32_t u = __builtin_bit_cast(uint32_t, x);
  uint32_t r = (u + 0x7FFFu + ((u >> 16) & 1u)) >> 16;   // RNE
  return (unsigned short)r;
}
__device__ __forceinline__ float sigm(float x) { return 1.0f / (1.0f + __expf(-x)); }

#define VM_DRAIN() asm volatile("s_waitcnt vmcnt(0)" ::: "memory")

// data-plane store: uni -> dirty line in shared XCD L2; else -> LLC coherent
__device__ __forceinline__ void ex_store(void* p, u32x2 v, bool uni) {
  if (uni) asm volatile("global_store_dwordx2 %0, %1, off sc0"     :: "v"(p), "v"(v) : "memory");
  else     asm volatile("global_store_dwordx2 %0, %1, off sc0 sc1" :: "v"(p), "v"(v) : "memory");
}
__device__ __forceinline__ void llc_store_f32(float* p, float v) {
  asm volatile("global_store_dword %0, %1, off sc0 sc1" :: "v"(p), "v"(v) : "memory");
}
// control plane: agent scope at the LLC, always
__device__ __forceinline__ void flag_add(int* p) {
  __hip_atomic_fetch_add(p, 1, __ATOMIC_RELAXED, __HIP_MEMORY_SCOPE_AGENT);
}
__device__ __forceinline__ int flag_peek(const int* p) {
  return __hip_atomic_load(p, __ATOMIC_RELAXED, __HIP_MEMORY_SCOPE_AGENT);
}
// R10 change: fast path + grace polls, then 4x-backoff sleep. Cuts device-wide
// poll pressure on the 16 hot LLC flag lines ~4x in the waiting regime while
// keeping already-set discovery at one load.
__device__ __forceinline__ void flag_wait(const int* p, int tgt) {
  if (flag_peek(p) >= tgt) return;
#pragma unroll 1
  for (int i = 0; i < 4; ++i)
    if (flag_peek(p) >= tgt) return;
  int sp = 0;
  while (flag_peek(p) < tgt) {
    __builtin_amdgcn_s_sleep(8);
    if (++sp > SPIN_CAP) break;        // bounded
  }
}

__device__ __forceinline__ u32x2 packbf4(fx4 v) {
  u32x2 r;
  r[0] = (uint32_t)f2bf(v[0]) | ((uint32_t)f2bf(v[1]) << 16);
  r[1] = (uint32_t)f2bf(v[2]) | ((uint32_t)f2bf(v[3]) << 16);
  return r;
}

// 32x32 out-tile partials; wave w handles K-slice [256w,256w+256).
// A (global, chunked, 1KB contiguous per load inst); B (LDS, chunked
// identically). Partials to red4[w][row*32+col]
// (C: col=lane&31, row=(reg&3)+8*(reg>>2)+4*(lane>>5)).
template <bool UNI>
__device__ __forceinline__ void gemm_phase(const short* __restrict__ abuf,
                                           const short* __restrict__ wl,
                                           float* __restrict__ red4, int tid) {
  const int lane = tid & 63, w = tid >> 6;
  const int m = lane & 31, h = lane >> 5;
  const short* ap = abuf + (32 * w + h) * 256 + m * 8;
  const short* bp = wl + (32 * w + h) * 256 + m * 8;
  short8 A[16];
  if (UNI) {
#pragma unroll
    for (int i = 0; i < 16; ++i)
      asm volatile("global_load_dwordx4 %0, %1, off sc0"
                   : "=v"(A[i]) : "v"(ap + i * 512) : "memory");
  } else {
#pragma unroll
    for (int i = 0; i < 16; ++i)
      asm volatile("global_load_dwordx4 %0, %1, off sc0 sc1"
                   : "=v"(A[i]) : "v"(ap + i * 512) : "memory");
  }
  asm volatile("s_waitcnt vmcnt(0)"
               : "+v"(A[0]), "+v"(A[1]), "+v"(A[2]), "+v"(A[3]),
                 "+v"(A[4]), "+v"(A[5]), "+v"(A[6]), "+v"(A[7]),
                 "+v"(A[8]), "+v"(A[9]), "+v"(A[10]), "+v"(A[11]),
                 "+v"(A[12]), "+v"(A[13]), "+v"(A[14]), "+v"(A[15])
               :: "memory");
  fx16 acc = 0.0f;
#pragma unroll
  for (int i = 0; i < 16; ++i) {
    short8 b = *(const short8*)(bp + i * 512);
    acc = __builtin_amdgcn_mfma_f32_32x32x16_bf16(A[i], b, acc, 0, 0, 0);
  }
#pragma unroll
  for (int i = 0; i < 16; ++i)
    red4[w * 1024 + ((i & 3) + 8 * (i >> 2) + 4 * h) * 32 + m] = acc[i];
}

extern "C" __global__ void __launch_bounds__(256)
hpcrnn_kernel(const int* __restrict__ cue,
              const float* __restrict__ ec3_last,
              const float* __restrict__ ec5_last,
              const float* __restrict__ ca1bias,
              const float* __restrict__ wca3ca1,
              const float* __restrict__ wec3ca1,
              const float* __restrict__ wca1ec5,
              const float* __restrict__ wca1act,
              const float* __restrict__ actbias,
              float* __restrict__ out,
              char* __restrict__ ws)
{
  extern __shared__ __attribute__((aligned(16))) char lds[];
  short* w1l  = (short*)(lds + LDS_W1);
  short* w2l  = (short*)(lds + LDS_W2);
  float* red4 = (float*)(lds + LDS_RED4);
  float* drvl = (float*)(lds + LDS_DRV);
  int*   unil = (int*)(lds + LDS_UNI);

  const int tid = threadIdx.x;
  const int bi  = blockIdx.x & 7;    // batch group; %8 == XCD residue heuristic
  const int nj  = blockIdx.x >> 3;   // N chunk (32 cols)
  const int R   = bi * 32, C = nj * 32;

  short* ec3buf = (short*)(ws + OFF_EC3);
  short* ca1buf = (short*)(ws + OFF_CA1);
  float* driveg = (float*)(ws + OFF_DRIVE);
  int*   ec3flag = (int*)(ws + OFF_EC3F);
  int*   ca1flag = (int*)(ws + OFF_CA1F);
  int*   drvflag = (int*)(ws + OFF_DRVF);
  int*   grpmask = (int*)(ws + OFF_GRP);
  int*   grpcnt  = (int*)(ws + OFF_GRP + 512);
  const int fbase = bi * 32;

  // ---- post group membership (XCD id), agent scope ----
  if (tid == 0) {
    int xcc;
    asm volatile("s_getreg_b32 %0, hwreg(HW_REG_XCC_ID)" : "=s"(xcc));
    __hip_atomic_fetch_or(&grpmask[bi], 1 << (xcc & 31), __ATOMIC_RELAXED, __HIP_MEMORY_SCOPE_AGENT);
    __hip_atomic_fetch_add(&grpcnt[bi], 1, __ATOMIC_RELAXED, __HIP_MEMORY_SCOPE_AGENT);
  }

  // ---- weights -> LDS, bf16, CHUNKED [g=(k>>3)][n=0..31][k&7] ----
  {
    const int c = tid & 31;
    for (int k = tid >> 5; k < FEAT; k += 8) {
      const int idx = ((k >> 3) * 32 + c) * 8 + (k & 7);
      w1l[idx] = (short)f2bf(wec3ca1[k * FEAT + C + c]);
      w2l[idx] = (short)f2bf(wca1ec5[k * FEAT + C + c]);
    }
  }

  // ---- resolve group XCD-uniformity (bounded; cap -> uni=false fallback) ----
  if (tid == 0) {
    flag_wait(&grpcnt[bi], 32);
    int cnt = flag_peek(&grpcnt[bi]);
    int mv  = __hip_atomic_load(&grpmask[bi], __ATOMIC_RELAXED, __HIP_MEMORY_SCOPE_AGENT);
    unil[0] = (cnt >= 32 && __popc(mv) == 1) ? 1 : 0;
  }
  __syncthreads();
  const bool uni = (unil[0] != 0);

  // ---- per-thread element mapping: 1 row x 4 consecutive cols ----
  const int r  = tid >> 3;
  const int c0 = (tid & 7) * 4;
  const int rg = R + r;
  const int cg = C + c0;
  const size_t stoff = (size_t)(((cg >> 3) * 32 + r) * 8 + (c0 & 7));
  const size_t gbase = (size_t)bi * GSTRIDE;
  const int lane = tid & 63, wv = tid >> 6;

  const fx4 biasv  = *(const fx4*)(ca1bias + cg);
  const fx4 wact01 = *(const fx4*)(wca1act + cg * 2);
  const fx4 wact23 = *(const fx4*)(wca1act + cg * 2 + 4);
  fx4 ec3v = *(const fx4*)(ec3_last + (size_t)rg * FEAT + cg);
  fx4 ec5v = *(const fx4*)(ec5_last + (size_t)rg * FEAT + cg);
  fx4 ca1v = 0.0f;

  // ---- publish initial ec3 (per-wave: wave drains its rows, lane0 adds) ----
  ex_store(ec3buf + gbase + stoff, packbf4(ec3v), uni);
  VM_DRAIN();
  if (lane == 0) flag_add(&ec3flag[fbase + nj]);

  // ---- drive precompute: t === bi (mod 8), cols C..C+31 (always LLC path) ----
  {
    float* dred = red4;
    const int g = tid >> 5, n = tid & 31;
    for (int t = bi; t < NSTEP; t += 8) {
      float part = 0.0f;
      const float tf = (float)t;
      for (int c = g * 128; c < g * 128 + 128; ++c) {
        float d = (float)c * (100.0f / 1023.0f) - tf;
        part += __expf(d * d * -0.02f) * wca3ca1[c * FEAT + C + n];
      }
      __syncthreads();
      dred[g * 32 + n] = part;
      __syncthreads();
      if (g == 0) {
        float s = 0.0f;
#pragma unroll
        for (int gg = 0; gg < 8; ++gg) s += dred[gg * 32 + n];
        llc_store_f32(driveg + t * FEAT + C + n, s);
      }
    }
    VM_DRAIN();
    __syncthreads();
    if (tid == 0) {
      flag_add(&drvflag[nj]);
      flag_wait(&drvflag[nj], 8);
    }
    __syncthreads();
    for (int i = tid; i < NSTEP * 32; i += 256) {
      float v;
      asm volatile("global_load_dword %0, %1, off sc0 sc1"
                   : "=v"(v) : "v"(driveg + (i >> 5) * FEAT + C + (i & 31)) : "memory");
      asm volatile("s_waitcnt vmcnt(0)" : "+v"(v) :: "memory");
      drvl[i] = v;
    }
    __syncthreads();
  }

  // =================== main recurrence ===================
  for (int t = 0; t < NSTEP; ++t) {
    const size_t par = (size_t)(t & 1) * PSTRIDE;
    const int tgt = 4 * (t + 1);

    // ---- phase 1: ca1 = relu(drive*(1+sig(ec3@w1)) - bias) ----
    // wave wv's K-slice depends only on producers nj' in [8wv, 8wv+8)
    if (lane < 8) flag_wait(&ec3flag[fbase + 8 * wv + lane], tgt);
    if (uni) gemm_phase<true >(ec3buf + par + gbase, w1l, red4, tid);
    else     gemm_phase<false>(ec3buf + par + gbase, w1l, red4, tid);
    __syncthreads();                                  // partials ready

    {
      const int e0 = 4 * tid;
      fx4 p0 = *(const fx4*)(red4 + e0);
      fx4 p1 = *(const fx4*)(red4 + 1024 + e0);
      fx4 p2 = *(const fx4*)(red4 + 2048 + e0);
      fx4 p3 = *(const fx4*)(red4 + 3072 + e0);
      const fx4 dv = *(const fx4*)(drvl + t * 32 + c0);
#pragma unroll
      for (int j = 0; j < 4; ++j) {
        float dot = (p0[j] + p1[j]) + (p2[j] + p3[j]);
        float v = dv[j] * (1.0f + sigm(dot)) - biasv[j];
        ca1v[j] = fmaxf(v, 0.0f);
      }
      ex_store(ca1buf + par + gbase + stoff, packbf4(ca1v), uni);
    }
    VM_DRAIN();                                       // this wave's rows landed
    if (lane == 0) flag_add(&ca1flag[fbase + nj]);    // early per-wave publish
    if (rg == 0) *(fx4*)(out + O_CAH + t * FEAT + cg) = ca1v;   // off critical path
    __syncthreads();                                  // red4 reuse protection

    // ---- phase 2: ec5 += ca1@w2 ; squash ; ec3 = ec5*ec3 ; cue mask ----
    if (lane < 8) flag_wait(&ca1flag[fbase + 8 * wv + lane], tgt);
    if (uni) gemm_phase<true >(ca1buf + par + gbase, w2l, red4, tid);
    else     gemm_phase<false>(ca1buf + par + gbase, w2l, red4, tid);
    __syncthreads();                                  // partials ready

    {
      const int e0 = 4 * tid;
      fx4 p0 = *(const fx4*)(red4 + e0);
      fx4 p1 = *(const fx4*)(red4 + 1024 + e0);
      fx4 p2 = *(const fx4*)(red4 + 2048 + e0);
      fx4 p3 = *(const fx4*)(red4 + 3072 + e0);
#pragma unroll
      for (int j = 0; j < 4; ++j) {
        float e5 = ec5v[j] + ((p0[j] + p1[j]) + (p2[j] + p3[j]));  // 10*TS = 1.0
        e5 = 0.69f + 0.3f * sigm(4.0f * (e5 - 0.3f));
        ec5v[j] = e5;
        ec3v[j] = e5 * ec3v[j];
      }
      if (t == 16 || t == 24) {
        const int s = (t == 24) ? 1 : 0;
        i32x4 m = *(const i32x4*)(cue + (size_t)rg * 2048 + s * 1024 + cg);
#pragma unroll
        for (int j = 0; j < 4; ++j)
          if (m[j]) ec3v[j] = 0.4f * ec3v[j] + 0.6f;
      }
      if (t < NSTEP - 1) {
        const size_t parn = (size_t)((t + 1) & 1) * PSTRIDE;
        ex_store(ec3buf + parn + gbase + stoff, packbf4(ec3v), uni);
      }
    }
    VM_DRAIN();
    if (lane == 0 && t < NSTEP - 1) flag_add(&ec3flag[fbase + nj]);  // early publish
    if (rg == 0) {                                    // off critical path
      *(fx4*)(out + O_E3H + t * FEAT + cg) = ec3v;
      *(fx4*)(out + O_E5H + t * FEAT + cg) = ec5v;
    }
    __syncthreads();                                  // red4 reuse protection
  }

  // ---- epilogue: finals + actCell ----
  float* ared = red4;
  if (tid < 64) ared[tid] = 0.0f;
  __syncthreads();
  {
    float p0 = ca1v[0] * wact01[0] + ca1v[1] * wact01[2] +
               ca1v[2] * wact23[0] + ca1v[3] * wact23[2];
    float p1 = ca1v[0] * wact01[1] + ca1v[1] * wact01[3] +
               ca1v[2] * wact23[1] + ca1v[3] * wact23[3];
    atomicAdd(&ared[r * 2 + 0], p0);
    atomicAdd(&ared[r * 2 + 1], p1);
  }
  *(fx4*)(out + O_E3 + (size_t)rg * FEAT + cg) = ec3v;
  *(fx4*)(out + O_E5 + (size_t)rg * FEAT + cg) = ec5v;
  *(fx4*)(out + O_CA + (size_t)rg * FEAT + cg) = ca1v;
  __syncthreads();
  if (tid < 64) {
    float v = ared[tid];
    if (nj == 0) v += actbias[tid & 1];
    atomicAdd(&out[O_ACT + (R + (tid >> 1)) * 2 + (tid & 1)], v);
  }
}

extern "C" void kernel_launch(void* const* d_in, const int* in_sizes, int n_in,
                              void* d_out, int out_size, void* d_ws, size_t ws_size,
                              hipStream_t stream) {
  (void)in_sizes; (void)n_in; (void)out_size;
  if (ws_size < WS_NEED) return;

  const int*   cue      = (const int*)  d_in[0];
  const float* ec3_last = (const float*)d_in[1];
  const float* ec5_last = (const float*)d_in[2];
  // d_in[3] = ca1_last: dead in the reference (overwritten before use)
  const float* ca1bias  = (const float*)d_in[4];
  const float* wca3ca1  = (const float*)d_in[5];
  const float* wec3ca1  = (const float*)d_in[6];
  const float* wca1ec5  = (const float*)d_in[7];
  const float* wca1act  = (const float*)d_in[8];
  const float* actbias  = (const float*)d_in[9];

  char* ws = (char*)d_ws;
  hipMemsetAsync(ws + OFF_EC3F, 0, 4 * 4096, stream);   // flags + rendezvous start at 0
  hipMemsetAsync(d_out, 0, 512 * sizeof(float), stream);

  hipFuncSetAttribute(reinterpret_cast<const void*>(hpcrnn_kernel),
                      hipFuncAttributeMaxDynamicSharedMemorySize, LDS_TOTAL);

  hipLaunchKernelGGL(hpcrnn_kernel, dim3(256), dim3(256), LDS_TOTAL, stream,
                     cue, ec3_last, ec5_last, ca1bias, wca3ca1, wec3ca1,
                     wca1ec5, wca1act, actbias, (float*)d_out, ws);
}

// Round 11
// 746.214 us; speedup vs baseline: 2.7048x; 1.0059x over previous
//
#include <hip/hip_runtime.h>
#include <stdint.h>

// ---------------- problem constants ----------------
#define NSTEP 100
#define FEAT  1024
#define SPIN_CAP  (1 << 16)   // LLC poll bound (~11ms worst) - truly bounded
#define CAP_FAST  512         // L2-flag probe bound (~85us once, then sticky fallback)

typedef __attribute__((ext_vector_type(8)))  short short8;
typedef __attribute__((ext_vector_type(4)))  float fx4;
typedef __attribute__((ext_vector_type(16))) float fx16;
typedef __attribute__((ext_vector_type(2)))  unsigned int u32x2;
typedef __attribute__((ext_vector_type(4)))  int i32x4;

// ---------------- workspace layout (bytes) ----------------
// R11 = R7 (best, 740us) + dual-scope flag publish with sticky fallback.
// Evidence: ~38MB of HBM FETCH is flag traffic -> agent-scope flag ops are
// HBM-class; the two prior XCD-local-flag attempts (R4/R6) "hangs" are
// consistent with unbounded stale-spin (4M-iter caps), not deadlock. This
// round probes L2-local flags SAFELY: producers update BOTH an L2 flag
// (global_atomic_add, no sc bits -> executes in XCD L2) and the proven LLC
// mirror; consumers try the L2 flag for CAP_FAST iters, then set a sticky
// block-local bit and use the LLC mirror forever. Worst case ~= R7 + 85us.
// DATA plane unchanged: XCD-L2 sc0 when group XCD-uniform (R5-proven), else sc1.
// Element (group-local row m, col c) at short index ((c>>3)*32+m)*8+(c&7).
#define OFF_EC3   0u
#define OFF_CA1   (1u << 20)
#define OFF_DRIVE (2u << 20)
#define OFF_EC3F  (OFF_DRIVE + (512u << 10))   // LLC mirrors
#define OFF_CA1F  (OFF_EC3F + 4096u)
#define OFF_DRVF  (OFF_CA1F + 4096u)
#define OFF_GRP   (OFF_DRVF + 4096u)           // grpmask[8] @+0, grpcnt[8] @+512
#define OFF_E3F2  (OFF_GRP + 4096u)            // L2-local ec3 flags [bi*32+nj]
#define OFF_C1F2  (OFF_E3F2 + 4096u)           // L2-local ca1 flags
#define WS_NEED   (OFF_C1F2 + 4096u)

#define GSTRIDE 32768                  // shorts per group (32*1024)
#define PSTRIDE (8 * GSTRIDE)          // shorts per parity buffer

// ---------------- output layout (float elems) ----------------
#define O_ACT 0
#define O_E3H 512
#define O_E5H (512 + 102400)
#define O_CAH (512 + 204800)
#define O_E3  (512 + 307200)
#define O_E5  (O_E3 + 262144)
#define O_CA  (O_E5 + 262144)

// ---------------- LDS layout (bytes) ----------------
#define LDS_W1    0
#define LDS_W2    65536
#define LDS_RED4  131072               // 4*1024 f32 = 16384
#define LDS_DRV   147456               // 100*32 f32 = 12800
#define LDS_UNI   160256               // int[2]: [0]=uni, [1]=sticky fallback
#define LDS_TOTAL 160264               // <= 163840

__device__ __forceinline__ unsigned short f2bf(float x) {
  uint32_t u = __builtin_bit_cast(uint32_t, x);
  uint32_t r = (u + 0x7FFFu + ((u >> 16) & 1u)) >> 16;   // RNE
  return (unsigned short)r;
}
__device__ __forceinline__ float sigm(float x) { return 1.0f / (1.0f + __expf(-x)); }

#define VM_DRAIN() asm volatile("s_waitcnt vmcnt(0)" ::: "memory")

// data-plane store: uni -> dirty line in shared XCD L2; else -> LLC coherent
__device__ __forceinline__ void ex_store(void* p, u32x2 v, bool uni) {
  if (uni) asm volatile("global_store_dwordx2 %0, %1, off sc0"     :: "v"(p), "v"(v) : "memory");
  else     asm volatile("global_store_dwordx2 %0, %1, off sc0 sc1" :: "v"(p), "v"(v) : "memory");
}
__device__ __forceinline__ void llc_store_f32(float* p, float v) {
  asm volatile("global_store_dword %0, %1, off sc0 sc1" :: "v"(p), "v"(v) : "memory");
}
// ---- control plane ----
__device__ __forceinline__ void flag_add(int* p) {               // LLC (proven)
  __hip_atomic_fetch_add(p, 1, __ATOMIC_RELAXED, __HIP_MEMORY_SCOPE_AGENT);
}
__device__ __forceinline__ int flag_peek(const int* p) {
  return __hip_atomic_load(p, __ATOMIC_RELAXED, __HIP_MEMORY_SCOPE_AGENT);
}
__device__ __forceinline__ void flag_wait(const int* p, int tgt) {   // LLC (proven)
  int sp = 0;
  while (flag_peek(p) < tgt) {
    __builtin_amdgcn_s_sleep(1);
    if (++sp > SPIN_CAP) break;        // bounded
  }
}
// dual publish: L2-local atomic (probe) + LLC mirror (ground truth)
__device__ __forceinline__ void flag_pub2(int* pL2, int* pLLC, bool uni) {
  if (uni) {
    int one = 1;
    asm volatile("global_atomic_add %0, %1, off" :: "v"(pL2), "v"(one) : "memory");
  }
  flag_add(pLLC);
}
__device__ __forceinline__ int l2_flag_rd(const int* p) {
  int v;
  asm volatile("global_load_dword %0, %1, off sc0" : "=v"(v) : "v"(p) : "memory");
  asm volatile("s_waitcnt vmcnt(0)" : "+v"(v) :: "memory");
  return v;
}
// consumer wait: try L2 flag (bounded), sticky-fallback to LLC mirror
__device__ __forceinline__ void flag_wait2(const int* pL2, const int* pLLC, int tgt,
                                           bool uni, volatile int* sticky) {
  if (uni && sticky[0] == 0) {
    int sp = 0;
    for (;;) {
      if (l2_flag_rd(pL2) >= tgt) return;
      __builtin_amdgcn_s_sleep(1);
      if (++sp > CAP_FAST) { sticky[0] = 1; break; }   // benign race, monotone
    }
  }
  flag_wait(pLLC, tgt);
}

__device__ __forceinline__ u32x2 packbf4(fx4 v) {
  u32x2 r;
  r[0] = (uint32_t)f2bf(v[0]) | ((uint32_t)f2bf(v[1]) << 16);
  r[1] = (uint32_t)f2bf(v[2]) | ((uint32_t)f2bf(v[3]) << 16);
  return r;
}

// 32x32 out-tile partials; wave w handles K-slice [256w,256w+256).
// A (global, chunked, 1KB contiguous per load inst); B (LDS, chunked
// identically). Partials to red4[w][row*32+col]
// (C: col=lane&31, row=(reg&3)+8*(reg>>2)+4*(lane>>5)).
template <bool UNI>
__device__ __forceinline__ void gemm_phase(const short* __restrict__ abuf,
                                           const short* __restrict__ wl,
                                           float* __restrict__ red4, int tid) {
  const int lane = tid & 63, w = tid >> 6;
  const int m = lane & 31, h = lane >> 5;
  const short* ap = abuf + (32 * w + h) * 256 + m * 8;
  const short* bp = wl + (32 * w + h) * 256 + m * 8;
  short8 A[16];
  if (UNI) {
#pragma unroll
    for (int i = 0; i < 16; ++i)
      asm volatile("global_load_dwordx4 %0, %1, off sc0"
                   : "=v"(A[i]) : "v"(ap + i * 512) : "memory");
  } else {
#pragma unroll
    for (int i = 0; i < 16; ++i)
      asm volatile("global_load_dwordx4 %0, %1, off sc0 sc1"
                   : "=v"(A[i]) : "v"(ap + i * 512) : "memory");
  }
  asm volatile("s_waitcnt vmcnt(0)"
               : "+v"(A[0]), "+v"(A[1]), "+v"(A[2]), "+v"(A[3]),
                 "+v"(A[4]), "+v"(A[5]), "+v"(A[6]), "+v"(A[7]),
                 "+v"(A[8]), "+v"(A[9]), "+v"(A[10]), "+v"(A[11]),
                 "+v"(A[12]), "+v"(A[13]), "+v"(A[14]), "+v"(A[15])
               :: "memory");
  fx16 acc = 0.0f;
#pragma unroll
  for (int i = 0; i < 16; ++i) {
    short8 b = *(const short8*)(bp + i * 512);
    acc = __builtin_amdgcn_mfma_f32_32x32x16_bf16(A[i], b, acc, 0, 0, 0);
  }
#pragma unroll
  for (int i = 0; i < 16; ++i)
    red4[w * 1024 + ((i & 3) + 8 * (i >> 2) + 4 * h) * 32 + m] = acc[i];
}

extern "C" __global__ void __launch_bounds__(256)
hpcrnn_kernel(const int* __restrict__ cue,
              const float* __restrict__ ec3_last,
              const float* __restrict__ ec5_last,
              const float* __restrict__ ca1bias,
              const float* __restrict__ wca3ca1,
              const float* __restrict__ wec3ca1,
              const float* __restrict__ wca1ec5,
              const float* __restrict__ wca1act,
              const float* __restrict__ actbias,
              float* __restrict__ out,
              char* __restrict__ ws)
{
  extern __shared__ __attribute__((aligned(16))) char lds[];
  short* w1l  = (short*)(lds + LDS_W1);
  short* w2l  = (short*)(lds + LDS_W2);
  float* red4 = (float*)(lds + LDS_RED4);
  float* drvl = (float*)(lds + LDS_DRV);
  volatile int* unil = (volatile int*)(lds + LDS_UNI);   // [0]=uni, [1]=sticky

  const int tid = threadIdx.x;
  const int bi  = blockIdx.x & 7;    // batch group; %8 == XCD residue heuristic
  const int nj  = blockIdx.x >> 3;   // N chunk (32 cols)
  const int R   = bi * 32, C = nj * 32;

  short* ec3buf = (short*)(ws + OFF_EC3);
  short* ca1buf = (short*)(ws + OFF_CA1);
  float* driveg = (float*)(ws + OFF_DRIVE);
  int*   ec3flag = (int*)(ws + OFF_EC3F);
  int*   ca1flag = (int*)(ws + OFF_CA1F);
  int*   drvflag = (int*)(ws + OFF_DRVF);
  int*   grpmask = (int*)(ws + OFF_GRP);
  int*   grpcnt  = (int*)(ws + OFF_GRP + 512);
  int*   e3f2    = (int*)(ws + OFF_E3F2);
  int*   c1f2    = (int*)(ws + OFF_C1F2);
  const int fbase = bi * 32;

  // ---- reset OWN L2 flag lines (sc0: claims the line in this XCD's L2) and
  //      only then post membership; the grpcnt==32 rendezvous below gates the
  //      main loop, so every reset happens-before any first flag_pub2 ----
  if (tid == 0) {
    unsigned int z = 0;
    asm volatile("global_store_dword %0, %1, off sc0" :: "v"(&e3f2[fbase + nj]), "v"(z) : "memory");
    asm volatile("global_store_dword %0, %1, off sc0" :: "v"(&c1f2[fbase + nj]), "v"(z) : "memory");
    VM_DRAIN();
    int xcc;
    asm volatile("s_getreg_b32 %0, hwreg(HW_REG_XCC_ID)" : "=s"(xcc));
    __hip_atomic_fetch_or(&grpmask[bi], 1 << (xcc & 31), __ATOMIC_RELAXED, __HIP_MEMORY_SCOPE_AGENT);
    __hip_atomic_fetch_add(&grpcnt[bi], 1, __ATOMIC_RELAXED, __HIP_MEMORY_SCOPE_AGENT);
  }

  // ---- weights -> LDS, bf16, CHUNKED [g=(k>>3)][n=0..31][k&7] ----
  {
    const int c = tid & 31;
    for (int k = tid >> 5; k < FEAT; k += 8) {
      const int idx = ((k >> 3) * 32 + c) * 8 + (k & 7);
      w1l[idx] = (short)f2bf(wec3ca1[k * FEAT + C + c]);
      w2l[idx] = (short)f2bf(wca1ec5[k * FEAT + C + c]);
    }
  }

  // ---- resolve group XCD-uniformity (rendezvous: all resets landed) ----
  if (tid == 0) {
    flag_wait(&grpcnt[bi], 32);
    int cnt = flag_peek(&grpcnt[bi]);
    int mv  = __hip_atomic_load(&grpmask[bi], __ATOMIC_RELAXED, __HIP_MEMORY_SCOPE_AGENT);
    unil[0] = (cnt >= 32 && __popc(mv) == 1) ? 1 : 0;
    unil[1] = 0;                        // sticky fallback bit
  }
  __syncthreads();
  const bool uni = (unil[0] != 0);

  // ---- per-thread element mapping: 1 row x 4 consecutive cols ----
  const int r  = tid >> 3;
  const int c0 = (tid & 7) * 4;
  const int rg = R + r;
  const int cg = C + c0;
  const size_t stoff = (size_t)(((cg >> 3) * 32 + r) * 8 + (c0 & 7));
  const size_t gbase = (size_t)bi * GSTRIDE;
  const int lane = tid & 63, wv = tid >> 6;

  const fx4 biasv  = *(const fx4*)(ca1bias + cg);
  const fx4 wact01 = *(const fx4*)(wca1act + cg * 2);
  const fx4 wact23 = *(const fx4*)(wca1act + cg * 2 + 4);
  fx4 ec3v = *(const fx4*)(ec3_last + (size_t)rg * FEAT + cg);
  fx4 ec5v = *(const fx4*)(ec5_last + (size_t)rg * FEAT + cg);
  fx4 ca1v = 0.0f;

  // ---- publish initial ec3 (per-wave: wave drains its rows, lane0 adds) ----
  ex_store(ec3buf + gbase + stoff, packbf4(ec3v), uni);
  VM_DRAIN();
  if (lane == 0) flag_pub2(&e3f2[fbase + nj], &ec3flag[fbase + nj], uni);

  // ---- drive precompute: t === bi (mod 8), cols C..C+31 (always LLC path) ----
  {
    float* dred = red4;
    const int g = tid >> 5, n = tid & 31;
    for (int t = bi; t < NSTEP; t += 8) {
      float part = 0.0f;
      const float tf = (float)t;
      for (int c = g * 128; c < g * 128 + 128; ++c) {
        float d = (float)c * (100.0f / 1023.0f) - tf;
        part += __expf(d * d * -0.02f) * wca3ca1[c * FEAT + C + n];
      }
      __syncthreads();
      dred[g * 32 + n] = part;
      __syncthreads();
      if (g == 0) {
        float s = 0.0f;
#pragma unroll
        for (int gg = 0; gg < 8; ++gg) s += dred[gg * 32 + n];
        llc_store_f32(driveg + t * FEAT + C + n, s);
      }
    }
    VM_DRAIN();
    __syncthreads();
    if (tid == 0) {
      flag_add(&drvflag[nj]);
      flag_wait(&drvflag[nj], 8);
    }
    __syncthreads();
    for (int i = tid; i < NSTEP * 32; i += 256) {
      float v;
      asm volatile("global_load_dword %0, %1, off sc0 sc1"
                   : "=v"(v) : "v"(driveg + (i >> 5) * FEAT + C + (i & 31)) : "memory");
      asm volatile("s_waitcnt vmcnt(0)" : "+v"(v) :: "memory");
      drvl[i] = v;
    }
    __syncthreads();
  }

  // =================== main recurrence ===================
  for (int t = 0; t < NSTEP; ++t) {
    const size_t par = (size_t)(t & 1) * PSTRIDE;
    const int tgt = 4 * (t + 1);

    // ---- phase 1: ca1 = relu(drive*(1+sig(ec3@w1)) - bias) ----
    // wave wv's K-slice depends only on producers nj' in [8wv, 8wv+8)
    if (lane < 8)
      flag_wait2(&e3f2[fbase + 8 * wv + lane], &ec3flag[fbase + 8 * wv + lane],
                 tgt, uni, unil + 1);
    if (uni) gemm_phase<true >(ec3buf + par + gbase, w1l, red4, tid);
    else     gemm_phase<false>(ec3buf + par + gbase, w1l, red4, tid);
    __syncthreads();                                  // partials ready

    {
      const int e0 = 4 * tid;
      fx4 p0 = *(const fx4*)(red4 + e0);
      fx4 p1 = *(const fx4*)(red4 + 1024 + e0);
      fx4 p2 = *(const fx4*)(red4 + 2048 + e0);
      fx4 p3 = *(const fx4*)(red4 + 3072 + e0);
      const fx4 dv = *(const fx4*)(drvl + t * 32 + c0);
#pragma unroll
      for (int j = 0; j < 4; ++j) {
        float dot = (p0[j] + p1[j]) + (p2[j] + p3[j]);
        float v = dv[j] * (1.0f + sigm(dot)) - biasv[j];
        ca1v[j] = fmaxf(v, 0.0f);
      }
      ex_store(ca1buf + par + gbase + stoff, packbf4(ca1v), uni);
    }
    VM_DRAIN();                                       // this wave's rows landed
    if (lane == 0) flag_pub2(&c1f2[fbase + nj], &ca1flag[fbase + nj], uni);
    if (rg == 0) *(fx4*)(out + O_CAH + t * FEAT + cg) = ca1v;   // off critical path
    __syncthreads();                                  // red4 reuse protection

    // ---- phase 2: ec5 += ca1@w2 ; squash ; ec3 = ec5*ec3 ; cue mask ----
    if (lane < 8)
      flag_wait2(&c1f2[fbase + 8 * wv + lane], &ca1flag[fbase + 8 * wv + lane],
                 tgt, uni, unil + 1);
    if (uni) gemm_phase<true >(ca1buf + par + gbase, w2l, red4, tid);
    else     gemm_phase<false>(ca1buf + par + gbase, w2l, red4, tid);
    __syncthreads();                                  // partials ready

    {
      const int e0 = 4 * tid;
      fx4 p0 = *(const fx4*)(red4 + e0);
      fx4 p1 = *(const fx4*)(red4 + 1024 + e0);
      fx4 p2 = *(const fx4*)(red4 + 2048 + e0);
      fx4 p3 = *(const fx4*)(red4 + 3072 + e0);
#pragma unroll
      for (int j = 0; j < 4; ++j) {
        float e5 = ec5v[j] + ((p0[j] + p1[j]) + (p2[j] + p3[j]));  // 10*TS = 1.0
        e5 = 0.69f + 0.3f * sigm(4.0f * (e5 - 0.3f));
        ec5v[j] = e5;
        ec3v[j] = e5 * ec3v[j];
      }
      if (t == 16 || t == 24) {
        const int s = (t == 24) ? 1 : 0;
        i32x4 m = *(const i32x4*)(cue + (size_t)rg * 2048 + s * 1024 + cg);
#pragma unroll
        for (int j = 0; j < 4; ++j)
          if (m[j]) ec3v[j] = 0.4f * ec3v[j] + 0.6f;
      }
      if (t < NSTEP - 1) {
        const size_t parn = (size_t)((t + 1) & 1) * PSTRIDE;
        ex_store(ec3buf + parn + gbase + stoff, packbf4(ec3v), uni);
      }
    }
    VM_DRAIN();
    if (lane == 0 && t < NSTEP - 1)
      flag_pub2(&e3f2[fbase + nj], &ec3flag[fbase + nj], uni);
    if (rg == 0) {                                    // off critical path
      *(fx4*)(out + O_E3H + t * FEAT + cg) = ec3v;
      *(fx4*)(out + O_E5H + t * FEAT + cg) = ec5v;
    }
    __syncthreads();                                  // red4 reuse protection
  }

  // ---- epilogue: finals + actCell ----
  float* ared = red4;
  if (tid < 64) ared[tid] = 0.0f;
  __syncthreads();
  {
    float p0 = ca1v[0] * wact01[0] + ca1v[1] * wact01[2] +
               ca1v[2] * wact23[0] + ca1v[3] * wact23[2];
    float p1 = ca1v[0] * wact01[1] + ca1v[1] * wact01[3] +
               ca1v[2] * wact23[1] + ca1v[3] * wact23[3];
    atomicAdd(&ared[r * 2 + 0], p0);
    atomicAdd(&ared[r * 2 + 1], p1);
  }
  *(fx4*)(out + O_E3 + (size_t)rg * FEAT + cg) = ec3v;
  *(fx4*)(out + O_E5 + (size_t)rg * FEAT + cg) = ec5v;
  *(fx4*)(out + O_CA + (size_t)rg * FEAT + cg) = ca1v;
  __syncthreads();
  if (tid < 64) {
    float v = ared[tid];
    if (nj == 0) v += actbias[tid & 1];
    atomicAdd(&out[O_ACT + (R + (tid >> 1)) * 2 + (tid & 1)], v);
  }
}

extern "C" void kernel_launch(void* const* d_in, const int* in_sizes, int n_in,
                              void* d_out, int out_size, void* d_ws, size_t ws_size,
                              hipStream_t stream) {
  (void)in_sizes; (void)n_in; (void)out_size;
  if (ws_size < WS_NEED) return;

  const int*   cue      = (const int*)  d_in[0];
  const float* ec3_last = (const float*)d_in[1];
  const float* ec5_last = (const float*)d_in[2];
  // d_in[3] = ca1_last: dead in the reference (overwritten before use)
  const float* ca1bias  = (const float*)d_in[4];
  const float* wca3ca1  = (const float*)d_in[5];
  const float* wec3ca1  = (const float*)d_in[6];
  const float* wca1ec5  = (const float*)d_in[7];
  const float* wca1act  = (const float*)d_in[8];
  const float* actbias  = (const float*)d_in[9];

  char* ws = (char*)d_ws;
  // zero LLC flags + rendezvous + both L2-flag arrays (LLC-visible zeros;
  // per-block sc0 resets handle any XCD-L2-resident staleness)
  hipMemsetAsync(ws + OFF_EC3F, 0, 6 * 4096, stream);
  hipMemsetAsync(d_out, 0, 512 * sizeof(float), stream);

  hipFuncSetAttribute(reinterpret_cast<const void*>(hpcrnn_kernel),
                      hipFuncAttributeMaxDynamicSharedMemorySize, LDS_TOTAL);

  hipLaunchKernelGGL(hpcrnn_kernel, dim3(256), dim3(256), LDS_TOTAL, stream,
                     cue, ec3_last, ec5_last, ca1bias, wca3ca1, wec3ca1,
                     wca1ec5, wca1act, actbias, (float*)d_out, ws);
}

// Round 12
// 732.365 us; speedup vs baseline: 2.7560x; 1.0189x over previous
//
#include <hip/hip_runtime.h>
#include <stdint.h>

// ---------------- problem constants ----------------
#define NSTEP 100
#define FEAT  1024
#define SPIN_CAP (1 << 16)   // bounded waits (~11ms worst)

typedef __attribute__((ext_vector_type(8)))  short short8;
typedef __attribute__((ext_vector_type(4)))  float fx4;
typedef __attribute__((ext_vector_type(16))) float fx16;
typedef __attribute__((ext_vector_type(2)))  unsigned int u32x2;
typedef __attribute__((ext_vector_type(4)))  int i32x4;

// ---------------- workspace layout (bytes) ----------------
// R12 = R7 (best, 740us) + fused poll/load: A-loads for each producer are
// issued the moment its flag is seen (ballot loop), so early producers' data
// streams in while waiting for the slowest. Post-discovery tail shrinks from
// (16-load stream + 16 MFMA) to (~2 loads + MFMAs).
// Hardware facts established R4-R11: DATA plane is XCD-L2-local (sc0, R5);
// flag SIGNALING must be agent-scope at the LLC/HBM (~1-1.5us/hop) -- L2-scope
// flag polling falsified 3x (R4 atomics, R6 stores, R11 probe+fallback);
// poll-rate/contention falsified (R10); single-wave and per-wave-tile
// structures regressed (R8/R9): 4-SIMD split-K + 2 barriers is the local opt.
// Exchange: parity dbuf, 8 groups x (32 rows x 1024 cols) bf16; flags count
// producer WAVES (tgt 4(t+1)).
// Element (group-local row m, col c) at short index ((c>>3)*32+m)*8+(c&7).
#define OFF_EC3   0u
#define OFF_CA1   (1u << 20)
#define OFF_DRIVE (2u << 20)
#define OFF_EC3F  (OFF_DRIVE + (512u << 10))
#define OFF_CA1F  (OFF_EC3F + 4096u)
#define OFF_DRVF  (OFF_CA1F + 4096u)
#define OFF_GRP   (OFF_DRVF + 4096u)   // grpmask[8] @+0, grpcnt[8] @+512
#define WS_NEED   (OFF_GRP + 4096u)

#define GSTRIDE 32768                  // shorts per group (32*1024)
#define PSTRIDE (8 * GSTRIDE)          // shorts per parity buffer

// ---------------- output layout (float elems) ----------------
#define O_ACT 0
#define O_E3H 512
#define O_E5H (512 + 102400)
#define O_CAH (512 + 204800)
#define O_E3  (512 + 307200)
#define O_E5  (O_E3 + 262144)
#define O_CA  (O_E5 + 262144)

// ---------------- LDS layout (bytes) ----------------
#define LDS_W1    0
#define LDS_W2    65536
#define LDS_RED4  131072               // 4*1024 f32 = 16384
#define LDS_DRV   147456               // 100*32 f32 = 12800
#define LDS_UNI   160256               // 1 int
#define LDS_TOTAL 160272               // <= 163840

__device__ __forceinline__ unsigned short f2bf(float x) {
  uint32_t u = __builtin_bit_cast(uint32_t, x);
  uint32_t r = (u + 0x7FFFu + ((u >> 16) & 1u)) >> 16;   // RNE
  return (unsigned short)r;
}
__device__ __forceinline__ float sigm(float x) { return 1.0f / (1.0f + __expf(-x)); }

#define VM_DRAIN() asm volatile("s_waitcnt vmcnt(0)" ::: "memory")

// data-plane store: uni -> dirty line in shared XCD L2; else -> LLC coherent
__device__ __forceinline__ void ex_store(void* p, u32x2 v, bool uni) {
  if (uni) asm volatile("global_store_dwordx2 %0, %1, off sc0"     :: "v"(p), "v"(v) : "memory");
  else     asm volatile("global_store_dwordx2 %0, %1, off sc0 sc1" :: "v"(p), "v"(v) : "memory");
}
__device__ __forceinline__ void llc_store_f32(float* p, float v) {
  asm volatile("global_store_dword %0, %1, off sc0 sc1" :: "v"(p), "v"(v) : "memory");
}
// control plane: agent scope at the LLC, always (the only HW-working protocol)
__device__ __forceinline__ void flag_add(int* p) {
  __hip_atomic_fetch_add(p, 1, __ATOMIC_RELAXED, __HIP_MEMORY_SCOPE_AGENT);
}
__device__ __forceinline__ int flag_peek(const int* p) {
  return __hip_atomic_load(p, __ATOMIC_RELAXED, __HIP_MEMORY_SCOPE_AGENT);
}
__device__ __forceinline__ void flag_wait(const int* p, int tgt) {
  int sp = 0;
  while (flag_peek(p) < tgt) {
    __builtin_amdgcn_s_sleep(1);
    if (++sp > SPIN_CAP) break;        // bounded
  }
}

__device__ __forceinline__ u32x2 packbf4(fx4 v) {
  u32x2 r;
  r[0] = (uint32_t)f2bf(v[0]) | ((uint32_t)f2bf(v[1]) << 16);
  r[1] = (uint32_t)f2bf(v[2]) | ((uint32_t)f2bf(v[3]) << 16);
  return r;
}

// Fused poll + GEMM phase. 32x32 out-tile partials; wave w handles K-slice
// [256w,256w+256), fed by producers nj' = 8w..8w+7 (producer p covers A-load
// pairs A[2p],A[2p+1]). Ballot loop: lane p (p<8) polls flag p; newly-ready
// producers get their loads issued immediately (fixed registers, MFMA order is
// position-determined so issue order is free). Fast path (all ready on entry)
// == R7's code + one ballot. Partials to red4[w][row*32+col]
// (C: col=lane&31, row=(reg&3)+8*(reg>>2)+4*(lane>>5)).
template <bool UNI>
__device__ __forceinline__ void gemm_phase_pipe(const short* __restrict__ abuf,
                                                const short* __restrict__ wl,
                                                float* __restrict__ red4, int tid,
                                                const int* __restrict__ flags, int tgt) {
  const int lane = tid & 63, w = tid >> 6;
  const int m = lane & 31, h = lane >> 5;
  const short* ap = abuf + (32 * w + h) * 256 + m * 8;
  const short* bp = wl + (32 * w + h) * 256 + m * 8;
  short8 A[16] = {};
  unsigned issuedm = 0;
  int sp = 0;

#define ISSUE_PAIR(p)                                                          \
  if (newly & (1u << (p))) {                                                   \
    if (UNI) {                                                                 \
      asm volatile("global_load_dwordx4 %0, %1, off sc0"                       \
                   : "=v"(A[2 * (p)]) : "v"(ap + (2 * (p)) * 512) : "memory"); \
      asm volatile("global_load_dwordx4 %0, %1, off sc0"                       \
                   : "=v"(A[2 * (p) + 1]) : "v"(ap + (2 * (p) + 1) * 512) : "memory"); \
    } else {                                                                   \
      asm volatile("global_load_dwordx4 %0, %1, off sc0 sc1"                   \
                   : "=v"(A[2 * (p)]) : "v"(ap + (2 * (p)) * 512) : "memory"); \
      asm volatile("global_load_dwordx4 %0, %1, off sc0 sc1"                   \
                   : "=v"(A[2 * (p) + 1]) : "v"(ap + (2 * (p) + 1) * 512) : "memory"); \
    }                                                                          \
  }

#pragma unroll 1
  while (issuedm != 0xFFu) {
    bool mine = (lane < 8) && (flag_peek(flags + lane) >= tgt);
    unsigned ready = (unsigned)(__ballot(mine) & 0xFFull);
    unsigned newly = ready & ~issuedm;
    if (newly) {
      ISSUE_PAIR(0) ISSUE_PAIR(1) ISSUE_PAIR(2) ISSUE_PAIR(3)
      ISSUE_PAIR(4) ISSUE_PAIR(5) ISSUE_PAIR(6) ISSUE_PAIR(7)
      issuedm |= newly;
    }
    if (issuedm != 0xFFu) {
      __builtin_amdgcn_s_sleep(1);
      if (++sp > SPIN_CAP) break;      // bounded: garbage result, not a hang
    }
  }
#undef ISSUE_PAIR

  asm volatile("s_waitcnt vmcnt(0)"
               : "+v"(A[0]), "+v"(A[1]), "+v"(A[2]), "+v"(A[3]),
                 "+v"(A[4]), "+v"(A[5]), "+v"(A[6]), "+v"(A[7]),
                 "+v"(A[8]), "+v"(A[9]), "+v"(A[10]), "+v"(A[11]),
                 "+v"(A[12]), "+v"(A[13]), "+v"(A[14]), "+v"(A[15])
               :: "memory");
  fx16 acc = 0.0f;
#pragma unroll
  for (int i = 0; i < 16; ++i) {
    short8 b = *(const short8*)(bp + i * 512);
    acc = __builtin_amdgcn_mfma_f32_32x32x16_bf16(A[i], b, acc, 0, 0, 0);
  }
#pragma unroll
  for (int i = 0; i < 16; ++i)
    red4[w * 1024 + ((i & 3) + 8 * (i >> 2) + 4 * h) * 32 + m] = acc[i];
}

extern "C" __global__ void __launch_bounds__(256)
hpcrnn_kernel(const int* __restrict__ cue,
              const float* __restrict__ ec3_last,
              const float* __restrict__ ec5_last,
              const float* __restrict__ ca1bias,
              const float* __restrict__ wca3ca1,
              const float* __restrict__ wec3ca1,
              const float* __restrict__ wca1ec5,
              const float* __restrict__ wca1act,
              const float* __restrict__ actbias,
              float* __restrict__ out,
              char* __restrict__ ws)
{
  extern __shared__ __attribute__((aligned(16))) char lds[];
  short* w1l  = (short*)(lds + LDS_W1);
  short* w2l  = (short*)(lds + LDS_W2);
  float* red4 = (float*)(lds + LDS_RED4);
  float* drvl = (float*)(lds + LDS_DRV);
  int*   unil = (int*)(lds + LDS_UNI);

  const int tid = threadIdx.x;
  const int bi  = blockIdx.x & 7;    // batch group; %8 == XCD residue heuristic
  const int nj  = blockIdx.x >> 3;   // N chunk (32 cols)
  const int R   = bi * 32, C = nj * 32;

  short* ec3buf = (short*)(ws + OFF_EC3);
  short* ca1buf = (short*)(ws + OFF_CA1);
  float* driveg = (float*)(ws + OFF_DRIVE);
  int*   ec3flag = (int*)(ws + OFF_EC3F);
  int*   ca1flag = (int*)(ws + OFF_CA1F);
  int*   drvflag = (int*)(ws + OFF_DRVF);
  int*   grpmask = (int*)(ws + OFF_GRP);
  int*   grpcnt  = (int*)(ws + OFF_GRP + 512);
  const int fbase = bi * 32;

  // ---- post group membership (XCD id), agent scope ----
  if (tid == 0) {
    int xcc;
    asm volatile("s_getreg_b32 %0, hwreg(HW_REG_XCC_ID)" : "=s"(xcc));
    __hip_atomic_fetch_or(&grpmask[bi], 1 << (xcc & 31), __ATOMIC_RELAXED, __HIP_MEMORY_SCOPE_AGENT);
    __hip_atomic_fetch_add(&grpcnt[bi], 1, __ATOMIC_RELAXED, __HIP_MEMORY_SCOPE_AGENT);
  }

  // ---- weights -> LDS, bf16, CHUNKED [g=(k>>3)][n=0..31][k&7] ----
  {
    const int c = tid & 31;
    for (int k = tid >> 5; k < FEAT; k += 8) {
      const int idx = ((k >> 3) * 32 + c) * 8 + (k & 7);
      w1l[idx] = (short)f2bf(wec3ca1[k * FEAT + C + c]);
      w2l[idx] = (short)f2bf(wca1ec5[k * FEAT + C + c]);
    }
  }

  // ---- resolve group XCD-uniformity (bounded; cap -> uni=false fallback) ----
  if (tid == 0) {
    flag_wait(&grpcnt[bi], 32);
    int cnt = flag_peek(&grpcnt[bi]);
    int mv  = __hip_atomic_load(&grpmask[bi], __ATOMIC_RELAXED, __HIP_MEMORY_SCOPE_AGENT);
    unil[0] = (cnt >= 32 && __popc(mv) == 1) ? 1 : 0;
  }
  __syncthreads();
  const bool uni = (unil[0] != 0);

  // ---- per-thread element mapping: 1 row x 4 consecutive cols ----
  const int r  = tid >> 3;
  const int c0 = (tid & 7) * 4;
  const int rg = R + r;
  const int cg = C + c0;
  const size_t stoff = (size_t)(((cg >> 3) * 32 + r) * 8 + (c0 & 7));
  const size_t gbase = (size_t)bi * GSTRIDE;
  const int lane = tid & 63, wv = tid >> 6;

  const fx4 biasv  = *(const fx4*)(ca1bias + cg);
  const fx4 wact01 = *(const fx4*)(wca1act + cg * 2);
  const fx4 wact23 = *(const fx4*)(wca1act + cg * 2 + 4);
  fx4 ec3v = *(const fx4*)(ec3_last + (size_t)rg * FEAT + cg);
  fx4 ec5v = *(const fx4*)(ec5_last + (size_t)rg * FEAT + cg);
  fx4 ca1v = 0.0f;

  // ---- publish initial ec3 (per-wave: wave drains its rows, lane0 adds) ----
  ex_store(ec3buf + gbase + stoff, packbf4(ec3v), uni);
  VM_DRAIN();
  if (lane == 0) flag_add(&ec3flag[fbase + nj]);

  // ---- drive precompute: t === bi (mod 8), cols C..C+31 (always LLC path) ----
  {
    float* dred = red4;
    const int g = tid >> 5, n = tid & 31;
    for (int t = bi; t < NSTEP; t += 8) {
      float part = 0.0f;
      const float tf = (float)t;
      for (int c = g * 128; c < g * 128 + 128; ++c) {
        float d = (float)c * (100.0f / 1023.0f) - tf;
        part += __expf(d * d * -0.02f) * wca3ca1[c * FEAT + C + n];
      }
      __syncthreads();
      dred[g * 32 + n] = part;
      __syncthreads();
      if (g == 0) {
        float s = 0.0f;
#pragma unroll
        for (int gg = 0; gg < 8; ++gg) s += dred[gg * 32 + n];
        llc_store_f32(driveg + t * FEAT + C + n, s);
      }
    }
    VM_DRAIN();
    __syncthreads();
    if (tid == 0) {
      flag_add(&drvflag[nj]);
      flag_wait(&drvflag[nj], 8);
    }
    __syncthreads();
    for (int i = tid; i < NSTEP * 32; i += 256) {
      float v;
      asm volatile("global_load_dword %0, %1, off sc0 sc1"
                   : "=v"(v) : "v"(driveg + (i >> 5) * FEAT + C + (i & 31)) : "memory");
      asm volatile("s_waitcnt vmcnt(0)" : "+v"(v) :: "memory");
      drvl[i] = v;
    }
    __syncthreads();
  }

  // =================== main recurrence ===================
  for (int t = 0; t < NSTEP; ++t) {
    const size_t par = (size_t)(t & 1) * PSTRIDE;
    const int tgt = 4 * (t + 1);

    // ---- phase 1: ca1 = relu(drive*(1+sig(ec3@w1)) - bias) ----
    // wave wv's K-slice depends only on producers nj' in [8wv, 8wv+8)
    if (uni) gemm_phase_pipe<true >(ec3buf + par + gbase, w1l, red4, tid,
                                    ec3flag + fbase + 8 * wv, tgt);
    else     gemm_phase_pipe<false>(ec3buf + par + gbase, w1l, red4, tid,
                                    ec3flag + fbase + 8 * wv, tgt);
    __syncthreads();                                  // partials ready

    {
      const int e0 = 4 * tid;
      fx4 p0 = *(const fx4*)(red4 + e0);
      fx4 p1 = *(const fx4*)(red4 + 1024 + e0);
      fx4 p2 = *(const fx4*)(red4 + 2048 + e0);
      fx4 p3 = *(const fx4*)(red4 + 3072 + e0);
      const fx4 dv = *(const fx4*)(drvl + t * 32 + c0);
#pragma unroll
      for (int j = 0; j < 4; ++j) {
        float dot = (p0[j] + p1[j]) + (p2[j] + p3[j]);
        float v = dv[j] * (1.0f + sigm(dot)) - biasv[j];
        ca1v[j] = fmaxf(v, 0.0f);
      }
      ex_store(ca1buf + par + gbase + stoff, packbf4(ca1v), uni);
    }
    VM_DRAIN();                                       // this wave's rows landed
    if (lane == 0) flag_add(&ca1flag[fbase + nj]);    // early per-wave publish
    if (rg == 0) *(fx4*)(out + O_CAH + t * FEAT + cg) = ca1v;   // off critical path
    __syncthreads();                                  // red4 reuse protection

    // ---- phase 2: ec5 += ca1@w2 ; squash ; ec3 = ec5*ec3 ; cue mask ----
    if (uni) gemm_phase_pipe<true >(ca1buf + par + gbase, w2l, red4, tid,
                                    ca1flag + fbase + 8 * wv, tgt);
    else     gemm_phase_pipe<false>(ca1buf + par + gbase, w2l, red4, tid,
                                    ca1flag + fbase + 8 * wv, tgt);
    __syncthreads();                                  // partials ready

    {
      const int e0 = 4 * tid;
      fx4 p0 = *(const fx4*)(red4 + e0);
      fx4 p1 = *(const fx4*)(red4 + 1024 + e0);
      fx4 p2 = *(const fx4*)(red4 + 2048 + e0);
      fx4 p3 = *(const fx4*)(red4 + 3072 + e0);
#pragma unroll
      for (int j = 0; j < 4; ++j) {
        float e5 = ec5v[j] + ((p0[j] + p1[j]) + (p2[j] + p3[j]));  // 10*TS = 1.0
        e5 = 0.69f + 0.3f * sigm(4.0f * (e5 - 0.3f));
        ec5v[j] = e5;
        ec3v[j] = e5 * ec3v[j];
      }
      if (t == 16 || t == 24) {
        const int s = (t == 24) ? 1 : 0;
        i32x4 m = *(const i32x4*)(cue + (size_t)rg * 2048 + s * 1024 + cg);
#pragma unroll
        for (int j = 0; j < 4; ++j)
          if (m[j]) ec3v[j] = 0.4f * ec3v[j] + 0.6f;
      }
      if (t < NSTEP - 1) {
        const size_t parn = (size_t)((t + 1) & 1) * PSTRIDE;
        ex_store(ec3buf + parn + gbase + stoff, packbf4(ec3v), uni);
      }
    }
    VM_DRAIN();
    if (lane == 0 && t < NSTEP - 1) flag_add(&ec3flag[fbase + nj]);  // early publish
    if (rg == 0) {                                    // off critical path
      *(fx4*)(out + O_E3H + t * FEAT + cg) = ec3v;
      *(fx4*)(out + O_E5H + t * FEAT + cg) = ec5v;
    }
    __syncthreads();                                  // red4 reuse protection
  }

  // ---- epilogue: finals + actCell ----
  float* ared = red4;
  if (tid < 64) ared[tid] = 0.0f;
  __syncthreads();
  {
    float p0 = ca1v[0] * wact01[0] + ca1v[1] * wact01[2] +
               ca1v[2] * wact23[0] + ca1v[3] * wact23[2];
    float p1 = ca1v[0] * wact01[1] + ca1v[1] * wact01[3] +
               ca1v[2] * wact23[1] + ca1v[3] * wact23[3];
    atomicAdd(&ared[r * 2 + 0], p0);
    atomicAdd(&ared[r * 2 + 1], p1);
  }
  *(fx4*)(out + O_E3 + (size_t)rg * FEAT + cg) = ec3v;
  *(fx4*)(out + O_E5 + (size_t)rg * FEAT + cg) = ec5v;
  *(fx4*)(out + O_CA + (size_t)rg * FEAT + cg) = ca1v;
  __syncthreads();
  if (tid < 64) {
    float v = ared[tid];
    if (nj == 0) v += actbias[tid & 1];
    atomicAdd(&out[O_ACT + (R + (tid >> 1)) * 2 + (tid & 1)], v);
  }
}

extern "C" void kernel_launch(void* const* d_in, const int* in_sizes, int n_in,
                              void* d_out, int out_size, void* d_ws, size_t ws_size,
                              hipStream_t stream) {
  (void)in_sizes; (void)n_in; (void)out_size;
  if (ws_size < WS_NEED) return;

  const int*   cue      = (const int*)  d_in[0];
  const float* ec3_last = (const float*)d_in[1];
  const float* ec5_last = (const float*)d_in[2];
  // d_in[3] = ca1_last: dead in the reference (overwritten before use)
  const float* ca1bias  = (const float*)d_in[4];
  const float* wca3ca1  = (const float*)d_in[5];
  const float* wec3ca1  = (const float*)d_in[6];
  const float* wca1ec5  = (const float*)d_in[7];
  const float* wca1act  = (const float*)d_in[8];
  const float* actbias  = (const float*)d_in[9];

  char* ws = (char*)d_ws;
  hipMemsetAsync(ws + OFF_EC3F, 0, 4 * 4096, stream);   // flags + rendezvous start at 0
  hipMemsetAsync(d_out, 0, 512 * sizeof(float), stream);

  hipFuncSetAttribute(reinterpret_cast<const void*>(hpcrnn_kernel),
                      hipFuncAttributeMaxDynamicSharedMemorySize, LDS_TOTAL);

  hipLaunchKernelGGL(hpcrnn_kernel, dim3(256), dim3(256), LDS_TOTAL, stream,
                     cue, ec3_last, ec5_last, ca1bias, wca3ca1, wec3ca1,
                     wca1ec5, wca1act, actbias, (float*)d_out, ws);
}